// Round 1
// baseline (152.201 us; speedup 1.0000x reference)
//
#include <hip/hip_runtime.h>

#define NQ   5
#define QD   6
#define NGEN 4
#define NW   (NGEN * QD * NQ)   // 120 weight angles

// One thread per batch sample. 32-amplitude real state held in registers.
// Weight-angle cos/sin (batch-uniform) staged in LDS once per block.
__global__ __launch_bounds__(256) void qsrgan_kernel(
    const float* __restrict__ inp,   // (B,1,4,4) = B*16 floats
    const float* __restrict__ qp,    // (4,30) = 120 floats
    float* __restrict__ out,         // (B,64)
    int B)
{
    __shared__ float cw[NW];
    __shared__ float sw[NW];
    const int t = threadIdx.x;
    if (t < NW) {
        float sv, cv;
        __sincosf(0.5f * qp[t], &sv, &cv);
        cw[t] = cv;
        sw[t] = sv;
    }
    __syncthreads();

    const int b = blockIdx.x * 256 + t;
    if (b >= B) return;

    // Bilinear upsample row 0, cols 0..4 -> only needs first 3 pixels of row 0.
    const float4 x = *reinterpret_cast<const float4*>(inp + (size_t)b * 16);
    float n0 = x.x;
    float n1 = 0.75f * x.x + 0.25f * x.y;
    float n2 = 0.25f * x.x + 0.75f * x.y;
    float n3 = 0.75f * x.y + 0.25f * x.z;
    float n4 = 0.25f * x.y + 0.75f * x.z;

    float cn[5], sn[5];
    __sincosf(0.5f * n0, &sn[0], &cn[0]);
    __sincosf(0.5f * n1, &sn[1], &cn[1]);
    __sincosf(0.5f * n2, &sn[2], &cn[2]);
    __sincosf(0.5f * n3, &sn[3], &cn[3]);
    __sincosf(0.5f * n4, &sn[4], &cn[4]);

    // Initial state after the 5 per-sample noise RYs on |00000> is a product
    // state: amp[i] = prod_w (bit_w(i) ? sin : cos)(n_w/2).
    // Flat index: wire w <-> bit (4-w)  (wire 0 is the MSB).
    float init[32];
#pragma unroll
    for (int i = 0; i < 32; ++i) {
        float a = ((i >> 4) & 1) ? sn[0] : cn[0];
        a *= ((i >> 3) & 1) ? sn[1] : cn[1];
        a *= ((i >> 2) & 1) ? sn[2] : cn[2];
        a *= ((i >> 1) & 1) ? sn[3] : cn[3];
        a *= ((i >> 0) & 1) ? sn[4] : cn[4];
        init[i] = a;
    }

    float* outb = out + (size_t)b * 64;

    for (int g = 0; g < NGEN; ++g) {
        float st[32];
#pragma unroll
        for (int i = 0; i < 32; ++i) st[i] = init[i];

        for (int d = 0; d < QD; ++d) {
            const int base = g * (QD * NQ) + d * NQ;
#pragma unroll
            for (int w = 0; w < NQ; ++w) {
                const float cc = cw[base + w];
                const float ss = sw[base + w];
                const int stride = 1 << (4 - w);
#pragma unroll
                for (int i = 0; i < 32; ++i) {
                    if (i & stride) continue;
                    float a0 = st[i];
                    float a1 = st[i + stride];
                    st[i]          = cc * a0 - ss * a1;
                    st[i + stride] = ss * a0 + cc * a1;
                }
            }
            // CZ on (w,w+1), w=0..3: negate amplitudes whose bits for wires
            // w and w+1 are both 1. Net sign = parity of adjacent-1 pairs.
#pragma unroll
            for (int i = 0; i < 32; ++i) {
                int flips = 0;
#pragma unroll
                for (int w = 0; w < NQ - 1; ++w) {
                    const int m = (1 << (4 - w)) | (1 << (3 - w));
                    flips ^= ((i & m) == m) ? 1 : 0;
                }
                if (flips) st[i] = -st[i];
            }
        }

        // probs[:16] / max  (the sum-normalization cancels exactly)
        float p[16];
        float mx = 0.0f;
#pragma unroll
        for (int i = 0; i < 16; ++i) {
            p[i] = st[i] * st[i];
            mx = fmaxf(mx, p[i]);
        }
        const float inv = 1.0f / mx;
#pragma unroll
        for (int i = 0; i < 16; i += 4) {
            float4 v = make_float4(p[i] * inv, p[i + 1] * inv,
                                   p[i + 2] * inv, p[i + 3] * inv);
            *reinterpret_cast<float4*>(outb + g * 16 + i) = v;
        }
    }
}

extern "C" void kernel_launch(void* const* d_in, const int* in_sizes, int n_in,
                              void* d_out, int out_size, void* d_ws, size_t ws_size,
                              hipStream_t stream) {
    const float* inp = (const float*)d_in[0];
    const float* qp  = (const float*)d_in[1];
    float* out = (float*)d_out;
    const int B = in_sizes[0] / 16;
    const int blocks = (B + 255) / 256;
    qsrgan_kernel<<<blocks, 256, 0, stream>>>(inp, qp, out, B);
}

// Round 2
// 110.948 us; speedup vs baseline: 1.3718x; 1.3718x over previous
//
#include <hip/hip_runtime.h>

#define NQ   5
#define QD   6
#define NGEN 4
#define NW   (NGEN * QD * NQ)   // 120 weight angles

// ---------------------------------------------------------------------------
// Kernel A: build M[g][j][t] = <j| U_g |t>  for j in 0..15 (only the first 16
// output amplitudes are used), t in 0..31. The weight circuit is batch-uniform
// so this 4 x 16 x 32 matrix fully captures it. One block, 128 threads:
// thread = (g, basis t).
// ---------------------------------------------------------------------------
__global__ __launch_bounds__(128) void qsrgan_build(
    const float* __restrict__ qp,   // (4,30)
    float* __restrict__ M)          // [4][16][32]
{
    __shared__ float cw[NW];
    __shared__ float sw[NW];
    const int t = threadIdx.x;
    if (t < NW) {
        float sv, cv;
        __sincosf(0.5f * qp[t], &sv, &cv);
        cw[t] = cv;
        sw[t] = sv;
    }
    __syncthreads();

    const int g = t >> 5;
    const int basis = t & 31;

    float st[32];
#pragma unroll
    for (int i = 0; i < 32; ++i) st[i] = (i == basis) ? 1.0f : 0.0f;

    for (int d = 0; d < QD; ++d) {
        const int base = g * (QD * NQ) + d * NQ;
#pragma unroll
        for (int w = 0; w < NQ; ++w) {
            const float cc = cw[base + w];
            const float ss = sw[base + w];
            const int stride = 1 << (4 - w);
#pragma unroll
            for (int i = 0; i < 32; ++i) {
                if (i & stride) continue;
                float a0 = st[i];
                float a1 = st[i + stride];
                st[i]          = cc * a0 - ss * a1;
                st[i + stride] = ss * a0 + cc * a1;
            }
        }
        // CZ(w,w+1) sign: parity of adjacent-11 bit pairs (compile-time per i)
#pragma unroll
        for (int i = 0; i < 32; ++i) {
            int flips = 0;
#pragma unroll
            for (int w = 0; w < NQ - 1; ++w) {
                const int m = (1 << (4 - w)) | (1 << (3 - w));
                flips ^= ((i & m) == m) ? 1 : 0;
            }
            if (flips) st[i] = -st[i];
        }
    }

#pragma unroll
    for (int j = 0; j < 16; ++j)
        M[g * 512 + j * 32 + basis] = st[j];
}

// ---------------------------------------------------------------------------
// Kernel B: per sample — product-state init (5 sincos + 60 muls), then
// out[g][j] = (sum_k M[g][j][k] * init[k])^2 / max_j. M accesses are
// wave-uniform (loop-indexed) -> scalar loads, FMAs use SGPR operand.
// ---------------------------------------------------------------------------
__global__ __launch_bounds__(256) void qsrgan_apply(
    const float* __restrict__ inp,  // (B,16)
    const float* __restrict__ M,    // [4][16][32]
    float* __restrict__ out,        // (B,64)
    int B)
{
    const int b = blockIdx.x * 256 + threadIdx.x;
    if (b >= B) return;

    // Bilinear-upsample row 0 cols 0..4 needs only x0,x1,x2 of the input row.
    const float4 x = *reinterpret_cast<const float4*>(inp + (size_t)b * 16);
    float n[5];
    n[0] = x.x;
    n[1] = 0.75f * x.x + 0.25f * x.y;
    n[2] = 0.25f * x.x + 0.75f * x.y;
    n[3] = 0.75f * x.y + 0.25f * x.z;
    n[4] = 0.25f * x.y + 0.75f * x.z;

    float cn[5], sn[5];
#pragma unroll
    for (int w = 0; w < 5; ++w) __sincosf(0.5f * n[w], &sn[w], &cn[w]);

    // init[i] = prod_w (bit_{4-w}(i) ? sin : cos); built as a tensor product.
    float a4[4], a8[8], a16[16], init[32];
    {
        float a2[2] = {cn[4], sn[4]};
#pragma unroll
        for (int i = 0; i < 4; ++i)  a4[i]  = ((i >> 1) ? sn[3] : cn[3]) * a2[i & 1];
#pragma unroll
        for (int i = 0; i < 8; ++i)  a8[i]  = ((i >> 2) ? sn[2] : cn[2]) * a4[i & 3];
#pragma unroll
        for (int i = 0; i < 16; ++i) a16[i] = ((i >> 3) ? sn[1] : cn[1]) * a8[i & 7];
#pragma unroll
        for (int i = 0; i < 32; ++i) init[i] = ((i >> 4) ? sn[0] : cn[0]) * a16[i & 15];
    }

    float* outb = out + (size_t)b * 64;

    for (int g = 0; g < NGEN; ++g) {
        const float* __restrict__ Mg = M + g * 512;
        float p[16];
        float mx = 0.0f;
#pragma unroll
        for (int j = 0; j < 16; ++j) {
            float acc = 0.0f;
#pragma unroll
            for (int k = 0; k < 32; ++k)
                acc += Mg[j * 32 + k] * init[k];
            p[j] = acc * acc;
            mx = fmaxf(mx, p[j]);
        }
        const float inv = 1.0f / mx;
#pragma unroll
        for (int i = 0; i < 16; i += 4) {
            float4 v = make_float4(p[i] * inv, p[i + 1] * inv,
                                   p[i + 2] * inv, p[i + 3] * inv);
            *reinterpret_cast<float4*>(outb + g * 16 + i) = v;
        }
    }
}

extern "C" void kernel_launch(void* const* d_in, const int* in_sizes, int n_in,
                              void* d_out, int out_size, void* d_ws, size_t ws_size,
                              hipStream_t stream) {
    const float* inp = (const float*)d_in[0];
    const float* qp  = (const float*)d_in[1];
    float* out = (float*)d_out;
    float* M   = (float*)d_ws;       // 4*16*32 floats = 8 KB
    const int B = in_sizes[0] / 16;

    qsrgan_build<<<1, 128, 0, stream>>>(qp, M);
    const int blocks = (B + 255) / 256;
    qsrgan_apply<<<blocks, 256, 0, stream>>>(inp, M, out, B);
}

// Round 3
// 96.695 us; speedup vs baseline: 1.5740x; 1.1474x over previous
//
#include <hip/hip_runtime.h>

#define NQ   5
#define QD   6
#define NGEN 4
#define NW   (NGEN * QD * NQ)   // 120 weight angles

// ---------------------------------------------------------------------------
// Kernel A: M[g][j][t] = <j| U_g |t>, j in 0..15, t in 0..31. Batch-uniform
// weight circuit fully captured by this 4 x 16 x 32 matrix. 1 block, 128 thr.
// ---------------------------------------------------------------------------
__global__ __launch_bounds__(128) void qsrgan_build(
    const float* __restrict__ qp,   // (4,30)
    float* __restrict__ M)          // [4][16][32]
{
    __shared__ float cw[NW];
    __shared__ float sw[NW];
    const int t = threadIdx.x;
    if (t < NW) {
        float sv, cv;
        __sincosf(0.5f * qp[t], &sv, &cv);
        cw[t] = cv;
        sw[t] = sv;
    }
    __syncthreads();

    const int g = t >> 5;
    const int basis = t & 31;

    float st[32];
#pragma unroll
    for (int i = 0; i < 32; ++i) st[i] = (i == basis) ? 1.0f : 0.0f;

    for (int d = 0; d < QD; ++d) {
        const int base = g * (QD * NQ) + d * NQ;
#pragma unroll
        for (int w = 0; w < NQ; ++w) {
            const float cc = cw[base + w];
            const float ss = sw[base + w];
            const int stride = 1 << (4 - w);
#pragma unroll
            for (int i = 0; i < 32; ++i) {
                if (i & stride) continue;
                float a0 = st[i];
                float a1 = st[i + stride];
                st[i]          = cc * a0 - ss * a1;
                st[i + stride] = ss * a0 + cc * a1;
            }
        }
#pragma unroll
        for (int i = 0; i < 32; ++i) {
            int flips = 0;
#pragma unroll
            for (int w = 0; w < NQ - 1; ++w) {
                const int m = (1 << (4 - w)) | (1 << (3 - w));
                flips ^= ((i & m) == m) ? 1 : 0;
            }
            if (flips) st[i] = -st[i];
        }
    }

#pragma unroll
    for (int j = 0; j < 16; ++j)
        M[g * 512 + j * 32 + basis] = st[j];
}

// ---------------------------------------------------------------------------
// Kernel B: block = 64 samples x 4 generators. Wave w (w = tid>>6) handles
// generator w for all 64 samples -> M base is wave-uniform (readfirstlane)
// -> scalar s_loads, v_fmac with SGPR operand. 512 FMAs/thread.
// Output staged through padded LDS transpose so global stores are
// lane-contiguous (full 128B lines per store instruction).
// ---------------------------------------------------------------------------
__global__ __launch_bounds__(256, 8) void qsrgan_apply(
    const float* __restrict__ inp,  // (B,16)
    const float* __restrict__ M,    // [4][16][32]
    float* __restrict__ out,        // (B,64)
    int B)
{
    __shared__ float pl[64 * 66];   // [c = g*16+j][s], stride 66 kills conflicts

    const int t    = threadIdx.x;
    const int lane = t & 63;
    const int g    = __builtin_amdgcn_readfirstlane(t >> 6);  // wave-uniform
    const int s0   = blockIdx.x * 64;
    const int b    = min(s0 + lane, B - 1);   // clamp (B is a multiple of 64)

    // Bilinear-upsample row 0 cols 0..4 needs only x0,x1,x2 of the input row.
    const float4 x = *reinterpret_cast<const float4*>(inp + (size_t)b * 16);
    float n[5];
    n[0] = x.x;
    n[1] = 0.75f * x.x + 0.25f * x.y;
    n[2] = 0.25f * x.x + 0.75f * x.y;
    n[3] = 0.75f * x.y + 0.25f * x.z;
    n[4] = 0.25f * x.y + 0.75f * x.z;

    float cn[5], sn[5];
#pragma unroll
    for (int w = 0; w < 5; ++w) __sincosf(0.5f * n[w], &sn[w], &cn[w]);

    // init[i] = prod_w (bit_{4-w}(i) ? sin : cos); tensor-product build.
    float a4[4], a8[8], a16[16], init[32];
    {
        float a2[2] = {cn[4], sn[4]};
#pragma unroll
        for (int i = 0; i < 4; ++i)  a4[i]  = ((i >> 1) ? sn[3] : cn[3]) * a2[i & 1];
#pragma unroll
        for (int i = 0; i < 8; ++i)  a8[i]  = ((i >> 2) ? sn[2] : cn[2]) * a4[i & 3];
#pragma unroll
        for (int i = 0; i < 16; ++i) a16[i] = ((i >> 3) ? sn[1] : cn[1]) * a8[i & 7];
#pragma unroll
        for (int i = 0; i < 32; ++i) init[i] = ((i >> 4) ? sn[0] : cn[0]) * a16[i & 15];
    }

    // 16x32 GEMV against this wave's generator matrix (scalar-loaded).
    const float* __restrict__ Mg = M + g * 512;
    float p[16];
    float mx = 0.0f;
#pragma unroll
    for (int j = 0; j < 16; ++j) {
        float acc = 0.0f;
#pragma unroll
        for (int k = 0; k < 32; ++k)
            acc += Mg[j * 32 + k] * init[k];
        p[j] = acc * acc;
        mx = fmaxf(mx, p[j]);
    }
    const float inv = 1.0f / mx;

    // Stage into LDS transposed: pl[(g*16+j)*66 + lane]  (2-way alias = free)
#pragma unroll
    for (int j = 0; j < 16; ++j)
        pl[(g * 16 + j) * 66 + lane] = p[j] * inv;

    __syncthreads();

    // Coalesced write-out: block region = 64 samples x 64 floats = 1024 float4
    const size_t base = (size_t)s0 * 64;
    float4* __restrict__ o4 = reinterpret_cast<float4*>(out + base);
#pragma unroll
    for (int i = 0; i < 4; ++i) {
        const int q    = t + i * 256;      // float4 index within block region
        const int srow = q >> 4;           // sample (q*4)/64
        const int c0   = (q & 15) << 2;    // channel (q*4)%64
        if (s0 + srow < B) {
            float4 v;
            v.x = pl[(c0 + 0) * 66 + srow];
            v.y = pl[(c0 + 1) * 66 + srow];
            v.z = pl[(c0 + 2) * 66 + srow];
            v.w = pl[(c0 + 3) * 66 + srow];
            o4[q] = v;
        }
    }
}

extern "C" void kernel_launch(void* const* d_in, const int* in_sizes, int n_in,
                              void* d_out, int out_size, void* d_ws, size_t ws_size,
                              hipStream_t stream) {
    const float* inp = (const float*)d_in[0];
    const float* qp  = (const float*)d_in[1];
    float* out = (float*)d_out;
    float* M   = (float*)d_ws;       // 4*16*32 floats = 8 KB
    const int B = in_sizes[0] / 16;

    qsrgan_build<<<1, 128, 0, stream>>>(qp, M);
    const int blocks = (B + 63) / 64;
    qsrgan_apply<<<blocks, 256, 0, stream>>>(inp, M, out, B);
}